// Round 2
// baseline (808.659 us; speedup 1.0000x reference)
//
#include <hip/hip_runtime.h>
#include <stdint.h>

// Llama attention block, bf16 MFMA pipeline.
// B=2 S=2048 D=2048 NH=16 NKV=4 HD=128
#define B_    2
#define S_    2048
#define D_    2048
#define NH_   16
#define NKV_  4
#define HD_   128
#define M_    (B_*S_)     // 4096 rows
#define NQKV_ 3072        // NH*HD + 2*NKV*HD

typedef __bf16 bf16x8 __attribute__((ext_vector_type(8)));
typedef float  f32x4  __attribute__((ext_vector_type(4)));

__device__ __forceinline__ unsigned short f2bf(float f) {
    unsigned int u = __float_as_uint(f);
    u += 0x7fffu + ((u >> 16) & 1u);   // round-to-nearest-even
    return (unsigned short)(u >> 16);
}

// ---- cast x (fp32) -> bf16, 4 elems/thread ----
__global__ void cast_x(const float* __restrict__ x, unsigned short* __restrict__ xb) {
    int idx = blockIdx.x * 256 + threadIdx.x;
    float4 v = ((const float4*)x)[idx];
    unsigned int lo = (unsigned int)f2bf(v.x) | ((unsigned int)f2bf(v.y) << 16);
    unsigned int hi = (unsigned int)f2bf(v.z) | ((unsigned int)f2bf(v.w) << 16);
    ((uint2*)xb)[idx] = make_uint2(lo, hi);
}

// ---- transpose fp32 [2048][ncols] -> bf16 [ncols][2048] (B^T layout for GEMM) ----
__global__ void transpose_cast(const float* __restrict__ src,
                               unsigned short* __restrict__ dst, int ncols) {
    __shared__ float tile[32][33];
    int tx = threadIdx.x, ty = threadIdx.y;
    int n0 = blockIdx.x * 32, k0 = blockIdx.y * 32;
#pragma unroll
    for (int i = 0; i < 4; i++) {
        int k = k0 + ty + i * 8;
        tile[ty + i * 8][tx] = src[(long)k * ncols + n0 + tx];
    }
    __syncthreads();
#pragma unroll
    for (int i = 0; i < 4; i++) {
        int n = n0 + ty + i * 8;
        dst[(long)n * 2048 + k0 + tx] = f2bf(tile[tx][ty + i * 8]);
    }
}

// ---- GEMM: C[M][N] fp32 = A[M][K] bf16 @ Bt[N][K] bf16 (B transposed) ----
__global__ __launch_bounds__(256) void gemm_bt(const unsigned short* __restrict__ A,
                                               const unsigned short* __restrict__ Bt,
                                               float* __restrict__ C, int N, int K) {
    __shared__ unsigned short As[128][40];   // +8 pad
    __shared__ unsigned short Bs[128][40];
    const int tid  = threadIdx.x;
    const int lane = tid & 63, wid = tid >> 6;
    const int quad = lane >> 4, l16 = lane & 15;
    const int wm = wid >> 1, wn = wid & 1;
    const int m0 = blockIdx.y * 128, n0 = blockIdx.x * 128;
    f32x4 acc[4][4] = {};
    const int arow = tid >> 2, acol = (tid & 3) * 8;

    for (int k0 = 0; k0 < K; k0 += 32) {
        __syncthreads();
        *(uint4*)&As[arow][acol]      = *(const uint4*)&A[(long)(m0 + arow) * K + k0 + acol];
        *(uint4*)&As[arow + 64][acol] = *(const uint4*)&A[(long)(m0 + arow + 64) * K + k0 + acol];
        *(uint4*)&Bs[arow][acol]      = *(const uint4*)&Bt[(long)(n0 + arow) * K + k0 + acol];
        *(uint4*)&Bs[arow + 64][acol] = *(const uint4*)&Bt[(long)(n0 + arow + 64) * K + k0 + acol];
        __syncthreads();
        bf16x8 af[4], bfr[4];
#pragma unroll
        for (int mt = 0; mt < 4; mt++)
            af[mt] = *(const bf16x8*)&As[wm * 64 + mt * 16 + l16][quad * 8];
#pragma unroll
        for (int nt = 0; nt < 4; nt++)
            bfr[nt] = *(const bf16x8*)&Bs[wn * 64 + nt * 16 + l16][quad * 8];
#pragma unroll
        for (int mt = 0; mt < 4; mt++)
#pragma unroll
            for (int nt = 0; nt < 4; nt++)
                acc[mt][nt] = __builtin_amdgcn_mfma_f32_16x16x32_bf16(af[mt], bfr[nt], acc[mt][nt], 0, 0, 0);
    }
#pragma unroll
    for (int mt = 0; mt < 4; mt++)
#pragma unroll
        for (int nt = 0; nt < 4; nt++)
#pragma unroll
            for (int r = 0; r < 4; r++) {
                long row = m0 + wm * 64 + mt * 16 + quad * 4 + r;
                long col = n0 + wn * 64 + nt * 16 + l16;
                C[row * N + col] = acc[mt][nt][r];
            }
}

// ---- RoPE on Q ----
__global__ void rope_q(const float* __restrict__ qkv, unsigned short* __restrict__ Qr) {
    int gid = blockIdx.x * 256 + threadIdx.x;
    int p = gid & 63;  int t1 = gid >> 6;
    int h = t1 & 15;   int t2 = t1 >> 4;
    int s = t2 & 2047; int b = t2 >> 11;
    float2 xv = *(const float2*)&qkv[(long)(b * 2048 + s) * 3072 + h * 128 + 2 * p];
    float inv = exp2f(-(float)p * 0.20762050593046014f);
    float ang = (float)s * inv;
    float sn, cs; sincosf(ang, &sn, &cs);
    float o0 = xv.x * cs - xv.y * sn;
    float o1 = xv.x * sn + xv.y * cs;
    unsigned int pk = (unsigned int)f2bf(o0) | ((unsigned int)f2bf(o1) << 16);
    *(unsigned int*)&Qr[(((long)(b * 16 + h) * 2048 + s) * 128) + 2 * p] = pk;
}

// ---- RoPE on K ----
__global__ void rope_k(const float* __restrict__ qkv, unsigned short* __restrict__ Kr) {
    int gid = blockIdx.x * 256 + threadIdx.x;
    int p = gid & 63;  int t1 = gid >> 6;
    int kvh = t1 & 3;  int t2 = t1 >> 2;
    int s = t2 & 2047; int b = t2 >> 11;
    float2 xv = *(const float2*)&qkv[(long)(b * 2048 + s) * 3072 + 2048 + kvh * 128 + 2 * p];
    float inv = exp2f(-(float)p * 0.20762050593046014f);
    float ang = (float)s * inv;
    float sn, cs; sincosf(ang, &sn, &cs);
    float o0 = xv.x * cs - xv.y * sn;
    float o1 = xv.x * sn + xv.y * cs;
    unsigned int pk = (unsigned int)f2bf(o0) | ((unsigned int)f2bf(o1) << 16);
    *(unsigned int*)&Kr[(((long)(b * 4 + kvh) * 2048 + s) * 128) + 2 * p] = pk;
}

// ---- V transpose: qkv cols 2560..3071 -> Vt bf16 [B][NKV][HD][S], coalesced both sides ----
__global__ void v_trans(const float* __restrict__ qkv, unsigned short* __restrict__ Vt) {
    __shared__ float tile[32][33];
    int tx = threadIdx.x, ty = threadIdx.y;
    int s0 = blockIdx.x * 32, d0 = blockIdx.y * 32;
    int bz = blockIdx.z;                       // b*NKV + kvh
    int b = bz >> 2, kvh = bz & 3;
#pragma unroll
    for (int i = 0; i < 4; i++) {
        int s = s0 + ty + i * 8;
        tile[ty + i * 8][tx] = qkv[(long)(b * 2048 + s) * 3072 + 2560 + kvh * 128 + d0 + tx];
    }
    __syncthreads();
#pragma unroll
    for (int i = 0; i < 4; i++) {
        int d = d0 + ty + i * 8;
        Vt[((long)bz * 128 + d) * 2048 + s0 + tx] = f2bf(tile[tx][ty + i * 8]);
    }
}

// ---- Flash attention: causal, GQA. Barrier-free: 4 independent waves/block,
// 16 q rows per wave, BKV=64, K/V read directly from global (L2-resident:
// total K+V = 4.2 MB). Ps (P layout round-trip) is wave-private LDS.
__global__ __launch_bounds__(256, 4) void attn_fwd(const unsigned short* __restrict__ Qr,
                                                   const unsigned short* __restrict__ Kr,
                                                   const unsigned short* __restrict__ Vt,
                                                   unsigned short* __restrict__ O) {
    __shared__ unsigned short Ps[4][16][72];  // per-wave P: q x kv (+8 pad)
    const int tid  = threadIdx.x;
    const int lane = tid & 63, wid = tid >> 6;
    const int quad = lane >> 4, l16 = lane & 15;
    const int qt = 31 - blockIdx.x;           // heavy blocks dispatched first
    const int h = blockIdx.y, b = blockIdx.z;
    const int kvh = h >> 2;                   // NH/NKV = 4
    const int qw = qt * 64 + wid * 16;        // this wave's 16 q rows
    const unsigned short* qp = Qr + (long)(b * NH_ + h) * S_ * HD_;
    const unsigned short* kp = Kr + (long)(b * NKV_ + kvh) * S_ * HD_;
    const unsigned short* vp = Vt + (long)(b * NKV_ + kvh) * HD_ * S_;

    bf16x8 aq[4];
#pragma unroll
    for (int ks = 0; ks < 4; ks++)
        aq[ks] = *(const bf16x8*)&qp[(long)(qw + l16) * HD_ + ks * 32 + quad * 8];

    f32x4 o[8] = {};
    float mi[4], li[4];
#pragma unroll
    for (int r = 0; r < 4; r++) { mi[r] = -3.0e38f; li[r] = 0.f; }
    // scale * log2(e): softmax in exp2 domain
    const float sc2 = 0.08838834764831845f * 1.4426950408889634f;
    const int ntile = (qw + 79) >> 6;         // kv-tiles covering kv <= qw+15

    for (int kt = 0; kt < ntile; kt++) {
        const int kv0 = kt * 64;

        // S = Q K^T (16 x 64), K fragments streamed from global (L2-hot)
        f32x4 s[4] = {};
#pragma unroll
        for (int ks = 0; ks < 4; ks++)
#pragma unroll
            for (int nt = 0; nt < 4; nt++) {
                bf16x8 kb = *(const bf16x8*)&kp[(long)(kv0 + nt * 16 + l16) * HD_ + ks * 32 + quad * 8];
                s[nt] = __builtin_amdgcn_mfma_f32_16x16x32_bf16(aq[ks], kb, s[nt], 0, 0, 0);
            }

        // online softmax in log2 domain (rows quad*4+r, cols nt*16+l16)
        float mt[4];
#pragma unroll
        for (int r = 0; r < 4; r++) mt[r] = -3.0e38f;
        if (kv0 + 63 > qw) {                  // diagonal tile(s): apply causal mask
#pragma unroll
            for (int nt = 0; nt < 4; nt++) {
                int kvp = kv0 + nt * 16 + l16;
#pragma unroll
                for (int r = 0; r < 4; r++) {
                    float sv = s[nt][r] * sc2;
                    sv = (kvp <= qw + quad * 4 + r) ? sv : -1.0e30f;
                    s[nt][r] = sv;
                    mt[r] = fmaxf(mt[r], sv);
                }
            }
        } else {
#pragma unroll
            for (int nt = 0; nt < 4; nt++)
#pragma unroll
                for (int r = 0; r < 4; r++) {
                    float sv = s[nt][r] * sc2;
                    s[nt][r] = sv;
                    mt[r] = fmaxf(mt[r], sv);
                }
        }
#pragma unroll
        for (int off = 1; off < 16; off <<= 1)
#pragma unroll
            for (int r = 0; r < 4; r++)
                mt[r] = fmaxf(mt[r], __shfl_xor(mt[r], off));
        float al[4], rs[4];
#pragma unroll
        for (int r = 0; r < 4; r++) {
            float mn = fmaxf(mi[r], mt[r]);
            al[r] = exp2f(mi[r] - mn);
            mi[r] = mn;
            rs[r] = 0.f;
        }
#pragma unroll
        for (int nt = 0; nt < 4; nt++)
#pragma unroll
            for (int r = 0; r < 4; r++) {
                float pv = exp2f(s[nt][r] - mi[r]);
                s[nt][r] = pv;
                rs[r] += pv;
            }
#pragma unroll
        for (int off = 1; off < 16; off <<= 1)
#pragma unroll
            for (int r = 0; r < 4; r++)
                rs[r] += __shfl_xor(rs[r], off);
#pragma unroll
        for (int r = 0; r < 4; r++) li[r] = li[r] * al[r] + rs[r];
#pragma unroll
        for (int t = 0; t < 8; t++)
#pragma unroll
            for (int r = 0; r < 4; r++) o[t][r] *= al[r];

        // P: C-layout -> wave-private LDS -> A-layout (no barrier needed)
#pragma unroll
        for (int nt = 0; nt < 4; nt++)
#pragma unroll
            for (int r = 0; r < 4; r++)
                Ps[wid][quad * 4 + r][nt * 16 + l16] = f2bf(s[nt][r]);

        // O += P V, V^T fragments streamed from global (L2-hot)
#pragma unroll
        for (int ks2 = 0; ks2 < 2; ks2++) {
            bf16x8 pa = *(const bf16x8*)&Ps[wid][l16][ks2 * 32 + quad * 8];
#pragma unroll
            for (int vt = 0; vt < 8; vt++) {
                bf16x8 vb = *(const bf16x8*)&vp[(long)(vt * 16 + l16) * S_ + kv0 + ks2 * 32 + quad * 8];
                o[vt] = __builtin_amdgcn_mfma_f32_16x16x32_bf16(pa, vb, o[vt], 0, 0, 0);
            }
        }
    }

    // epilogue: O/l -> attn buffer bf16 [b*S+s][h*128+hd]
#pragma unroll
    for (int r = 0; r < 4; r++) {
        float inv_l = 1.0f / li[r];
        int qpos = qw + quad * 4 + r;
#pragma unroll
        for (int vt = 0; vt < 8; vt++) {
            float val = o[vt][r] * inv_l;
            O[(long)(b * S_ + qpos) * 2048 + h * 128 + vt * 16 + l16] = f2bf(val);
        }
    }
}

extern "C" void kernel_launch(void* const* d_in, const int* in_sizes, int n_in,
                              void* d_out, int out_size, void* d_ws, size_t ws_size,
                              hipStream_t stream) {
    const float* x  = (const float*)d_in[0];
    // d_in[1] = mask: deterministic causal tril, applied analytically in attn_fwd.
    const float* Wq = (const float*)d_in[2];
    const float* Wk = (const float*)d_in[3];
    const float* Wv = (const float*)d_in[4];
    const float* Wo = (const float*)d_in[5];

    char* ws = (char*)d_ws;
    unsigned short* xb    = (unsigned short*)(ws);                 // 16,777,216 B
    unsigned short* Wqkvt = (unsigned short*)(ws + 16777216);      // 12,582,912 B
    unsigned short* Wot   = (unsigned short*)(ws + 29360128);      //  8,388,608 B
    float*          qkv   = (float*)         (ws + 37748736);      // 50,331,648 B
    unsigned short* Qr    = (unsigned short*)(ws + 88080384);      // 16,777,216 B
    unsigned short* Kr    = (unsigned short*)(ws + 104857600);     //  4,194,304 B
    unsigned short* Vt    = (unsigned short*)(ws + 109051904);     //  4,194,304 B
    unsigned short* attn  = (unsigned short*)(ws + 113246208);     // 16,777,216 B

    cast_x<<<8192, 256, 0, stream>>>(x, xb);
    dim3 tb(32, 8);
    transpose_cast<<<dim3(64, 64), tb, 0, stream>>>(Wq, Wqkvt, 2048);
    transpose_cast<<<dim3(16, 64), tb, 0, stream>>>(Wk, Wqkvt + 2048 * 2048, 512);
    transpose_cast<<<dim3(16, 64), tb, 0, stream>>>(Wv, Wqkvt + 2560 * 2048, 512);
    transpose_cast<<<dim3(64, 64), tb, 0, stream>>>(Wo, Wot, 2048);

    gemm_bt<<<dim3(NQKV_ / 128, M_ / 128), 256, 0, stream>>>(xb, Wqkvt, qkv, NQKV_, D_);

    rope_q<<<16384, 256, 0, stream>>>(qkv, Qr);
    rope_k<<<4096, 256, 0, stream>>>(qkv, Kr);
    v_trans<<<dim3(64, 4, 8), tb, 0, stream>>>(qkv, Vt);

    attn_fwd<<<dim3(S_ / 64, NH_, B_), 256, 0, stream>>>(Qr, Kr, Vt, attn);

    gemm_bt<<<dim3(D_ / 128, M_ / 128), 256, 0, stream>>>(attn, Wot, (float*)d_out, D_, NH_ * HD_);
}

// Round 3
// 386.905 us; speedup vs baseline: 2.0901x; 2.0901x over previous
//
#include <hip/hip_runtime.h>
#include <stdint.h>

// Llama attention block, bf16 MFMA pipeline.
// B=2 S=2048 D=2048 NH=16 NKV=4 HD=128
#define B_    2
#define S_    2048
#define D_    2048
#define NH_   16
#define NKV_  4
#define HD_   128
#define M_    (B_*S_)     // 4096 rows
#define NQKV_ 3072        // NH*HD + 2*NKV*HD

typedef __bf16 bf16x8 __attribute__((ext_vector_type(8)));
typedef float  f32x4  __attribute__((ext_vector_type(4)));

__device__ __forceinline__ unsigned short f2bf(float f) {
    unsigned int u = __float_as_uint(f);
    u += 0x7fffu + ((u >> 16) & 1u);   // round-to-nearest-even
    return (unsigned short)(u >> 16);
}

// async global->LDS, 16B per lane; LDS dest = wave-uniform base + lane*16
__device__ __forceinline__ void async_cp16(const unsigned short* g, unsigned short* l) {
    __builtin_amdgcn_global_load_lds((const __attribute__((address_space(1))) void*)g,
                                     (__attribute__((address_space(3))) void*)l, 16, 0, 0);
}

// ---- cast x (fp32) -> bf16, 4 elems/thread ----
__global__ void cast_x(const float* __restrict__ x, unsigned short* __restrict__ xb) {
    int idx = blockIdx.x * 256 + threadIdx.x;
    float4 v = ((const float4*)x)[idx];
    unsigned int lo = (unsigned int)f2bf(v.x) | ((unsigned int)f2bf(v.y) << 16);
    unsigned int hi = (unsigned int)f2bf(v.z) | ((unsigned int)f2bf(v.w) << 16);
    ((uint2*)xb)[idx] = make_uint2(lo, hi);
}

// ---- transpose fp32 [2048][ncols] -> bf16 [ncols][2048] (B^T layout for GEMM) ----
__global__ void transpose_cast(const float* __restrict__ src,
                               unsigned short* __restrict__ dst, int ncols) {
    __shared__ float tile[32][33];
    int tx = threadIdx.x, ty = threadIdx.y;
    int n0 = blockIdx.x * 32, k0 = blockIdx.y * 32;
#pragma unroll
    for (int i = 0; i < 4; i++) {
        int k = k0 + ty + i * 8;
        tile[ty + i * 8][tx] = src[(long)k * ncols + n0 + tx];
    }
    __syncthreads();
#pragma unroll
    for (int i = 0; i < 4; i++) {
        int n = n0 + ty + i * 8;
        dst[(long)n * 2048 + k0 + tx] = f2bf(tile[tx][ty + i * 8]);
    }
}

// ---- GEMM (m97 structure): C[M][N] fp32 = A[M][K] bf16 @ Bt[N][K] bf16 ----
// 128x128 tile, BK=32, global_load_lds width=16 staging, unpadded LDS.
__global__ __launch_bounds__(256) void gemm_bt(const unsigned short* __restrict__ A,
                                               const unsigned short* __restrict__ Bt,
                                               float* __restrict__ C, int N, int K) {
    __shared__ unsigned short As[128 * 32];
    __shared__ unsigned short Bs[128 * 32];
    const int tid  = threadIdx.x;
    const int lane = tid & 63, wid = tid >> 6;
    const int quad = lane >> 4, l16 = lane & 15;
    const int wm = wid >> 1, wn = wid & 1;
    const int m0 = blockIdx.y * 128, n0 = blockIdx.x * 128;
    f32x4 acc[4][4] = {};

    for (int k0 = 0; k0 < K; k0 += 32) {
        __syncthreads();
#pragma unroll
        for (int i = 0; i < 2; i++) {
            // granule g covers 8 bf16; tile row = g>>2 (32 cols = 4 granules/row)
            int gbase = (wid * 2 + i) * 64;
            int g = gbase + lane;
            int row = g >> 2, c = (g & 3) * 8;
            async_cp16(&A[(long)(m0 + row) * K + k0 + c], &As[gbase * 8]);
            async_cp16(&Bt[(long)(n0 + row) * K + k0 + c], &Bs[gbase * 8]);
        }
        __syncthreads();
        bf16x8 af[4], bfr[4];
#pragma unroll
        for (int mt = 0; mt < 4; mt++)
            af[mt] = *(const bf16x8*)&As[(wm * 64 + mt * 16 + l16) * 32 + quad * 8];
#pragma unroll
        for (int nt = 0; nt < 4; nt++)
            bfr[nt] = *(const bf16x8*)&Bs[(wn * 64 + nt * 16 + l16) * 32 + quad * 8];
#pragma unroll
        for (int mt = 0; mt < 4; mt++)
#pragma unroll
            for (int nt = 0; nt < 4; nt++)
                acc[mt][nt] = __builtin_amdgcn_mfma_f32_16x16x32_bf16(af[mt], bfr[nt], acc[mt][nt], 0, 0, 0);
    }
#pragma unroll
    for (int mt = 0; mt < 4; mt++)
#pragma unroll
        for (int nt = 0; nt < 4; nt++)
#pragma unroll
            for (int r = 0; r < 4; r++) {
                long row = m0 + wm * 64 + mt * 16 + quad * 4 + r;
                long col = n0 + wn * 64 + nt * 16 + l16;
                C[row * N + col] = acc[mt][nt][r];
            }
}

// ---- RoPE on Q ----
__global__ void rope_q(const float* __restrict__ qkv, unsigned short* __restrict__ Qr) {
    int gid = blockIdx.x * 256 + threadIdx.x;
    int p = gid & 63;  int t1 = gid >> 6;
    int h = t1 & 15;   int t2 = t1 >> 4;
    int s = t2 & 2047; int b = t2 >> 11;
    float2 xv = *(const float2*)&qkv[(long)(b * 2048 + s) * 3072 + h * 128 + 2 * p];
    float inv = exp2f(-(float)p * 0.20762050593046014f);
    float ang = (float)s * inv;
    float sn, cs; sincosf(ang, &sn, &cs);
    float o0 = xv.x * cs - xv.y * sn;
    float o1 = xv.x * sn + xv.y * cs;
    unsigned int pk = (unsigned int)f2bf(o0) | ((unsigned int)f2bf(o1) << 16);
    *(unsigned int*)&Qr[(((long)(b * 16 + h) * 2048 + s) * 128) + 2 * p] = pk;
}

// ---- RoPE on K ----
__global__ void rope_k(const float* __restrict__ qkv, unsigned short* __restrict__ Kr) {
    int gid = blockIdx.x * 256 + threadIdx.x;
    int p = gid & 63;  int t1 = gid >> 6;
    int kvh = t1 & 3;  int t2 = t1 >> 2;
    int s = t2 & 2047; int b = t2 >> 11;
    float2 xv = *(const float2*)&qkv[(long)(b * 2048 + s) * 3072 + 2048 + kvh * 128 + 2 * p];
    float inv = exp2f(-(float)p * 0.20762050593046014f);
    float ang = (float)s * inv;
    float sn, cs; sincosf(ang, &sn, &cs);
    float o0 = xv.x * cs - xv.y * sn;
    float o1 = xv.x * sn + xv.y * cs;
    unsigned int pk = (unsigned int)f2bf(o0) | ((unsigned int)f2bf(o1) << 16);
    *(unsigned int*)&Kr[(((long)(b * 4 + kvh) * 2048 + s) * 128) + 2 * p] = pk;
}

// ---- V transpose: qkv cols 2560..3071 -> Vt bf16 [B][NKV][HD][S] ----
__global__ void v_trans(const float* __restrict__ qkv, unsigned short* __restrict__ Vt) {
    __shared__ float tile[32][33];
    int tx = threadIdx.x, ty = threadIdx.y;
    int s0 = blockIdx.x * 32, d0 = blockIdx.y * 32;
    int bz = blockIdx.z;                       // b*NKV + kvh
    int b = bz >> 2, kvh = bz & 3;
#pragma unroll
    for (int i = 0; i < 4; i++) {
        int s = s0 + ty + i * 8;
        tile[ty + i * 8][tx] = qkv[(long)(b * 2048 + s) * 3072 + 2560 + kvh * 128 + d0 + tx];
    }
    __syncthreads();
#pragma unroll
    for (int i = 0; i < 4; i++) {
        int d = d0 + ty + i * 8;
        Vt[((long)bz * 128 + d) * 2048 + s0 + tx] = f2bf(tile[tx][ty + i * 8]);
    }
}

// ---- Flash attention: causal, GQA. LDS-staged K/V (R1 structure).
// Work-balanced: block pid handles q-strips {31-pid, pid} sequentially ->
// every block does exactly 33 kv-iterations (uniform). 2 barriers/iter
// (Ps is wave-private: no 3rd barrier). Grid 512 uniform blocks.
__global__ __launch_bounds__(256) void attn_fwd(const unsigned short* __restrict__ Qr,
                                                const unsigned short* __restrict__ Kr,
                                                const unsigned short* __restrict__ Vt,
                                                unsigned short* __restrict__ O) {
    __shared__ unsigned short Ks[64][136];    // kv x hd (+8 pad)
    __shared__ unsigned short Vs[128][72];    // hd x kv (+8 pad)
    __shared__ unsigned short Ps[4][16][72];  // per-wave P (wave-private)
    const int tid  = threadIdx.x;
    const int lane = tid & 63, wid = tid >> 6;
    const int quad = lane >> 4, l16 = lane & 15;
    const int pid = blockIdx.x, h = blockIdx.y, b = blockIdx.z;
    const int kvh = h >> 2;                   // NH/NKV = 4
    const unsigned short* qp = Qr + (long)(b * NH_ + h) * S_ * HD_;
    const unsigned short* kp = Kr + (long)(b * NKV_ + kvh) * S_ * HD_;
    const unsigned short* vp = Vt + (long)(b * NKV_ + kvh) * HD_ * S_;
    const float sc2 = 0.08838834764831845f * 1.4426950408889634f;  // scale*log2e

    for (int phase = 0; phase < 2; phase++) {
        const int qt = phase ? pid : 31 - pid;    // heavy strip first
        const int qw = qt * 64 + wid * 16;        // this wave's 16 q rows

        bf16x8 aq[4];
#pragma unroll
        for (int ks = 0; ks < 4; ks++)
            aq[ks] = *(const bf16x8*)&qp[(long)(qw + l16) * HD_ + ks * 32 + quad * 8];

        f32x4 o[8] = {};
        float mi[4], li[4];
#pragma unroll
        for (int r = 0; r < 4; r++) { mi[r] = -3.0e38f; li[r] = 0.f; }

        for (int kt = 0; kt <= qt; kt++) {
            const int kv0 = kt * 64;
            __syncthreads();
#pragma unroll
            for (int i = 0; i < 4; i++) {        // stage K tile: 64 x 128
                int idx = tid + i * 256;
                int row = idx >> 4, c = (idx & 15) * 8;
                *(uint4*)&Ks[row][c] = *(const uint4*)&kp[(long)(kv0 + row) * HD_ + c];
            }
#pragma unroll
            for (int i = 0; i < 4; i++) {        // stage V^T tile: 128 x 64
                int idx = tid + i * 256;
                int hd = idx >> 3, c = (idx & 7) * 8;
                *(uint4*)&Vs[hd][c] = *(const uint4*)&vp[(long)hd * S_ + kv0 + c];
            }
            __syncthreads();

            // S = Q K^T (16 x 64 per wave)
            f32x4 s[4] = {};
#pragma unroll
            for (int ks = 0; ks < 4; ks++)
#pragma unroll
                for (int nt = 0; nt < 4; nt++) {
                    bf16x8 kb = *(const bf16x8*)&Ks[nt * 16 + l16][ks * 32 + quad * 8];
                    s[nt] = __builtin_amdgcn_mfma_f32_16x16x32_bf16(aq[ks], kb, s[nt], 0, 0, 0);
                }

            // online softmax in exp2 domain
            float mt[4];
#pragma unroll
            for (int r = 0; r < 4; r++) mt[r] = -3.0e38f;
            if (kv0 + 63 > qw) {                 // diagonal tile: causal mask
#pragma unroll
                for (int nt = 0; nt < 4; nt++) {
                    int kvp = kv0 + nt * 16 + l16;
#pragma unroll
                    for (int r = 0; r < 4; r++) {
                        float sv = s[nt][r] * sc2;
                        sv = (kvp <= qw + quad * 4 + r) ? sv : -1.0e30f;
                        s[nt][r] = sv;
                        mt[r] = fmaxf(mt[r], sv);
                    }
                }
            } else {
#pragma unroll
                for (int nt = 0; nt < 4; nt++)
#pragma unroll
                    for (int r = 0; r < 4; r++) {
                        float sv = s[nt][r] * sc2;
                        s[nt][r] = sv;
                        mt[r] = fmaxf(mt[r], sv);
                    }
            }
#pragma unroll
            for (int off = 1; off < 16; off <<= 1)
#pragma unroll
                for (int r = 0; r < 4; r++)
                    mt[r] = fmaxf(mt[r], __shfl_xor(mt[r], off));
            float al[4], rs[4];
#pragma unroll
            for (int r = 0; r < 4; r++) {
                float mn = fmaxf(mi[r], mt[r]);
                al[r] = exp2f(mi[r] - mn);
                mi[r] = mn;
                rs[r] = 0.f;
            }
#pragma unroll
            for (int nt = 0; nt < 4; nt++)
#pragma unroll
                for (int r = 0; r < 4; r++) {
                    float pv = exp2f(s[nt][r] - mi[r]);
                    s[nt][r] = pv;
                    rs[r] += pv;
                }
#pragma unroll
            for (int off = 1; off < 16; off <<= 1)
#pragma unroll
                for (int r = 0; r < 4; r++)
                    rs[r] += __shfl_xor(rs[r], off);
#pragma unroll
            for (int r = 0; r < 4; r++) li[r] = li[r] * al[r] + rs[r];
#pragma unroll
            for (int t = 0; t < 8; t++)
#pragma unroll
                for (int r = 0; r < 4; r++) o[t][r] *= al[r];

            // P: C-layout -> wave-private LDS -> A-layout (no barrier)
#pragma unroll
            for (int nt = 0; nt < 4; nt++)
#pragma unroll
                for (int r = 0; r < 4; r++)
                    Ps[wid][quad * 4 + r][nt * 16 + l16] = f2bf(s[nt][r]);

            // O += P V  (16 x 128 per wave)
#pragma unroll
            for (int ks2 = 0; ks2 < 2; ks2++) {
                bf16x8 pa = *(const bf16x8*)&Ps[wid][l16][ks2 * 32 + quad * 8];
#pragma unroll
                for (int vt = 0; vt < 8; vt++) {
                    bf16x8 vb = *(const bf16x8*)&Vs[vt * 16 + l16][ks2 * 32 + quad * 8];
                    o[vt] = __builtin_amdgcn_mfma_f32_16x16x32_bf16(pa, vb, o[vt], 0, 0, 0);
                }
            }
        }

        // epilogue: O/l -> attn buffer bf16 [b*S+s][h*128+hd]
#pragma unroll
        for (int r = 0; r < 4; r++) {
            float inv_l = 1.0f / li[r];
            int qpos = qw + quad * 4 + r;
#pragma unroll
            for (int vt = 0; vt < 8; vt++) {
                float val = o[vt][r] * inv_l;
                O[(long)(b * S_ + qpos) * 2048 + h * 128 + vt * 16 + l16] = f2bf(val);
            }
        }
    }
}

extern "C" void kernel_launch(void* const* d_in, const int* in_sizes, int n_in,
                              void* d_out, int out_size, void* d_ws, size_t ws_size,
                              hipStream_t stream) {
    const float* x  = (const float*)d_in[0];
    // d_in[1] = mask: deterministic causal tril, applied analytically in attn_fwd.
    const float* Wq = (const float*)d_in[2];
    const float* Wk = (const float*)d_in[3];
    const float* Wv = (const float*)d_in[4];
    const float* Wo = (const float*)d_in[5];

    char* ws = (char*)d_ws;
    unsigned short* xb    = (unsigned short*)(ws);                 // 16,777,216 B
    unsigned short* Wqkvt = (unsigned short*)(ws + 16777216);      // 12,582,912 B
    unsigned short* Wot   = (unsigned short*)(ws + 29360128);      //  8,388,608 B
    float*          qkv   = (float*)         (ws + 37748736);      // 50,331,648 B
    unsigned short* Qr    = (unsigned short*)(ws + 88080384);      // 16,777,216 B
    unsigned short* Kr    = (unsigned short*)(ws + 104857600);     //  4,194,304 B
    unsigned short* Vt    = (unsigned short*)(ws + 109051904);     //  4,194,304 B
    unsigned short* attn  = (unsigned short*)(ws + 113246208);     // 16,777,216 B

    cast_x<<<8192, 256, 0, stream>>>(x, xb);
    dim3 tb(32, 8);
    transpose_cast<<<dim3(64, 64), tb, 0, stream>>>(Wq, Wqkvt, 2048);
    transpose_cast<<<dim3(16, 64), tb, 0, stream>>>(Wk, Wqkvt + 2048 * 2048, 512);
    transpose_cast<<<dim3(16, 64), tb, 0, stream>>>(Wv, Wqkvt + 2560 * 2048, 512);
    transpose_cast<<<dim3(64, 64), tb, 0, stream>>>(Wo, Wot, 2048);

    gemm_bt<<<dim3(NQKV_ / 128, M_ / 128), 256, 0, stream>>>(xb, Wqkvt, qkv, NQKV_, D_);

    rope_q<<<16384, 256, 0, stream>>>(qkv, Qr);
    rope_k<<<4096, 256, 0, stream>>>(qkv, Kr);
    v_trans<<<dim3(64, 4, 8), tb, 0, stream>>>(qkv, Vt);

    attn_fwd<<<dim3(16, NH_, B_), 256, 0, stream>>>(Qr, Kr, Vt, attn);

    gemm_bt<<<dim3(D_ / 128, M_ / 128), 256, 0, stream>>>(attn, Wot, (float*)d_out, D_, NH_ * HD_);
}